// Round 1
// baseline (1242.608 us; speedup 1.0000x reference)
//
#include <hip/hip_runtime.h>

#define HID 256
#define NB 1024
#define NM 64
#define NROWS (NB*NM)   // 65536
#define NACT 16
#define NSTEPS 4

// ---------------- prep: Aw = W1h - inv*W1c ; Wc = inv*W1c ----------------
__global__ __launch_bounds__(256) void prep_k(const float* __restrict__ W1,
                                              float* __restrict__ Aw,
                                              float* __restrict__ Wc) {
    int i = blockIdx.x * 256 + threadIdx.x;
    if (i >= HID * HID) return;
    int k = i >> 8, n = i & 255;
    const float inv = 1.0f / 63.0f;
    float wh = W1[k * HID + n];
    float wc = W1[(HID + k) * HID + n];
    Aw[i] = wh - inv * wc;
    Wc[i] = inv * wc;
}

// ---------------- embedding gather: h[r][:] = emb[ids[r]][:] ----------------
__global__ __launch_bounds__(256) void embed_k(const int* __restrict__ ids,
                                               const float* __restrict__ emb,
                                               float* __restrict__ h) {
    int idx = blockIdx.x * 256 + threadIdx.x;   // one float4 per thread
    if (idx >= NROWS * HID / 4) return;
    int r  = idx >> 6;      // 64 float4 per row
    int c4 = idx & 63;
    int id = ids[r];
    const float4* src = (const float4*)(emb + (size_t)id * HID);
    ((float4*)(h + (size_t)r * HID))[c4] = src[c4];
}

// ---------------- rowsum + tiny GEMM: T[b] = (sum_m h[b,m,:]) @ Wc ----------------
__global__ __launch_bounds__(256) void rowsumT_k(const float* __restrict__ h,
                                                 const float* __restrict__ Wc,
                                                 float* __restrict__ T) {
    int b = blockIdx.x;
    int t = threadIdx.x;
    __shared__ float S[HID];
    const float* hb = h + (size_t)b * NM * HID;
    float s = 0.f;
    #pragma unroll 8
    for (int m = 0; m < NM; ++m) s += hb[m * HID + t];
    S[t] = s;
    __syncthreads();
    float acc = 0.f;
    #pragma unroll 8
    for (int k = 0; k < HID; ++k) acc += S[k] * Wc[k * HID + t];
    T[b * HID + t] = acc;
}

// ---------------- main GEMM: C[M,N] = Amat[M,K] @ Bmat[K,N] + epilogue ----------------
// M=NROWS, N=K=256. 64x64 tile per block, 256 threads, 4x4 micro-tile.
// EPI 0: C = AB + bias                      (u0 = h0@W1h0 + b1)
// EPI 1: C = relu(AB + T[batch] + U0)      (act)
// EPI 2: C = AB + bias + Hres              (h += act@W2 + b2)
template<int EPI>
__global__ __launch_bounds__(256) void gemm64(const float* __restrict__ Amat,
                                              const float* __restrict__ Bmat,
                                              float* __restrict__ C,
                                              const float* __restrict__ bias,
                                              const float* __restrict__ Trow,
                                              const float* __restrict__ U0,
                                              const float* __restrict__ Hres) {
    __shared__ float As[16][64];
    __shared__ float Bs[16][64];

    const int tid = threadIdx.x;
    const int tx = tid & 15;        // 0..15 -> cols tx*4..+3
    const int ty = tid >> 4;        // 0..15 -> rows ty*4..+3
    const int row0 = blockIdx.x * 64;
    const int n0   = blockIdx.y * 64;

    float acc[4][4] = {};

    const int lr  = tid >> 2;   // 0..63 : A-tile row
    const int lkq = tid & 3;    // 0..3  : A-tile k-quad
    const int lk  = tid >> 4;   // 0..15 : B-tile k row
    const int lc  = tid & 15;   // 0..15 : B-tile col quad

    for (int k0 = 0; k0 < HID; k0 += 16) {
        float4 av = *(const float4*)(Amat + (size_t)(row0 + lr) * HID + k0 + lkq * 4);
        float4 bv = *(const float4*)(Bmat + (size_t)(k0 + lk) * HID + n0 + lc * 4);
        __syncthreads();
        As[lkq * 4 + 0][lr] = av.x;
        As[lkq * 4 + 1][lr] = av.y;
        As[lkq * 4 + 2][lr] = av.z;
        As[lkq * 4 + 3][lr] = av.w;
        *(float4*)&Bs[lk][lc * 4] = bv;
        __syncthreads();
        #pragma unroll
        for (int kk = 0; kk < 16; ++kk) {
            float4 a = *(const float4*)&As[kk][ty * 4];
            float4 b = *(const float4*)&Bs[kk][tx * 4];
            acc[0][0] += a.x * b.x; acc[0][1] += a.x * b.y; acc[0][2] += a.x * b.z; acc[0][3] += a.x * b.w;
            acc[1][0] += a.y * b.x; acc[1][1] += a.y * b.y; acc[1][2] += a.y * b.z; acc[1][3] += a.y * b.w;
            acc[2][0] += a.z * b.x; acc[2][1] += a.z * b.y; acc[2][2] += a.z * b.z; acc[2][3] += a.z * b.w;
            acc[3][0] += a.w * b.x; acc[3][1] += a.w * b.y; acc[3][2] += a.w * b.z; acc[3][3] += a.w * b.w;
        }
    }

    const int batch = row0 >> 6;   // 64 rows per batch, tile == batch
    #pragma unroll
    for (int i = 0; i < 4; ++i) {
        int row = row0 + ty * 4 + i;
        int col = n0 + tx * 4;
        float4 v = make_float4(acc[i][0], acc[i][1], acc[i][2], acc[i][3]);
        if (EPI == 0) {
            float4 bb = *(const float4*)(bias + col);
            v.x += bb.x; v.y += bb.y; v.z += bb.z; v.w += bb.w;
        } else if (EPI == 1) {
            float4 tt = *(const float4*)(Trow + batch * HID + col);
            float4 uu = *(const float4*)(U0 + (size_t)row * HID + col);
            v.x = fmaxf(v.x + tt.x + uu.x, 0.f);
            v.y = fmaxf(v.y + tt.y + uu.y, 0.f);
            v.z = fmaxf(v.z + tt.z + uu.z, 0.f);
            v.w = fmaxf(v.w + tt.w + uu.w, 0.f);
        } else {
            float4 bb = *(const float4*)(bias + col);
            float4 hh = *(const float4*)(Hres + (size_t)row * HID + col);
            v.x += bb.x + hh.x; v.y += bb.y + hh.y; v.z += bb.z + hh.z; v.w += bb.w + hh.w;
        }
        *(float4*)(C + (size_t)row * HID + col) = v;
    }
}

// ---------------- decoder: logits = h @ Wd + bd ----------------
__global__ __launch_bounds__(256) void decoder_k(const float* __restrict__ h,
                                                 const float* __restrict__ Wd,
                                                 const float* __restrict__ bd,
                                                 float* __restrict__ out) {
    __shared__ float hs[16][260];
    __shared__ float Wds[HID * NACT];
    const int tid = threadIdx.x;
    const int r0 = blockIdx.x * 16;
    // stage 16 rows of h (float4-coalesced)
    #pragma unroll
    for (int j = 0; j < 4; ++j) {
        int idx = tid + j * 256;        // 0..1023 float4s
        int r  = idx >> 6;
        int c4 = idx & 63;
        float4 v = *(const float4*)(h + (size_t)(r0 + r) * HID + c4 * 4);
        *(float4*)&hs[r][c4 * 4] = v;
    }
    // stage Wd (4096 floats)
    #pragma unroll
    for (int j = 0; j < 16; ++j) Wds[tid + j * 256] = Wd[tid + j * 256];
    __syncthreads();

    const int row = tid >> 4;   // 0..15
    const int a   = tid & 15;   // 0..15
    float acc = bd[a];
    #pragma unroll 8
    for (int k = 0; k < HID; ++k) acc += hs[row][k] * Wds[k * NACT + a];
    out[(size_t)(r0 + row) * NACT + a] = acc;
}

extern "C" void kernel_launch(void* const* d_in, const int* in_sizes, int n_in,
                              void* d_out, int out_size, void* d_ws, size_t ws_size,
                              hipStream_t stream) {
    const int*   ids = (const int*)d_in[0];
    const float* emb = (const float*)d_in[1];
    const float* W1  = (const float*)d_in[2];
    const float* b1  = (const float*)d_in[3];
    const float* W2  = (const float*)d_in[4];
    const float* b2  = (const float*)d_in[5];
    const float* Wd  = (const float*)d_in[6];
    const float* bd  = (const float*)d_in[7];
    float* out = (float*)d_out;

    float* ws  = (float*)d_ws;
    float* h   = ws;                                  // NROWS*HID
    float* u0  = h   + (size_t)NROWS * HID;           // NROWS*HID
    float* act = u0  + (size_t)NROWS * HID;           // NROWS*HID
    float* T   = act + (size_t)NROWS * HID;           // NB*HID
    float* Aw  = T   + (size_t)NB * HID;              // HID*HID
    float* Wc  = Aw  + (size_t)HID * HID;             // HID*HID
    // total ~194 MB

    const float* W1h0 = W1 + 2 * HID * HID;

    prep_k<<<(HID * HID + 255) / 256, 256, 0, stream>>>(W1, Aw, Wc);
    embed_k<<<(NROWS * HID / 4 + 255) / 256, 256, 0, stream>>>(ids, emb, h);

    dim3 g(NROWS / 64, HID / 64);
    // u0 = h0 @ W1h0 + b1   (h currently == h0)
    gemm64<0><<<g, 256, 0, stream>>>(h, W1h0, u0, b1, nullptr, nullptr, nullptr);

    for (int s = 0; s < NSTEPS; ++s) {
        rowsumT_k<<<NB, 256, 0, stream>>>(h, Wc, T);
        gemm64<1><<<g, 256, 0, stream>>>(h, Aw, act, nullptr, T, u0, nullptr);
        gemm64<2><<<g, 256, 0, stream>>>(act, W2, h, b2, nullptr, nullptr, h);
    }

    decoder_k<<<NROWS / 16, 256, 0, stream>>>(h, Wd, bd, out);
}

// Round 2
// 750.936 us; speedup vs baseline: 1.6547x; 1.6547x over previous
//
#include <hip/hip_runtime.h>

#define HID 256
#define NB 1024
#define NM 64
#define NROWS (NB*NM)   // 65536
#define NACT 16
#define NSTEPS 4
#define KS 768          // stacked K: [Ah*Bh | Ah*Bl | Al*Bh]
#define BM 128
#define BN 128
#define BK 32

typedef __bf16 bf16x8 __attribute__((ext_vector_type(8)));
typedef float  f32x4  __attribute__((ext_vector_type(4)));

__device__ __forceinline__ void gload_lds16(const void* g, void* l) {
    __builtin_amdgcn_global_load_lds(
        (const __attribute__((address_space(1))) void*)g,
        (__attribute__((address_space(3))) void*)l, 16, 0, 0);
}

__device__ __forceinline__ unsigned short f2bf(float x) {
    union { float f; unsigned u; } v; v.f = x;
    unsigned r = v.u + 0x7fff + ((v.u >> 16) & 1);   // RTNE
    return (unsigned short)(r >> 16);
}
__device__ __forceinline__ float bf2f(unsigned short b) {
    union { float f; unsigned u; } v; v.u = ((unsigned)b) << 16;
    return v.f;
}

// ---- prep: build stacked bf16 weights (Bt layout [n][k], K=768) + Wc f32 ----
// Wst[0] = Aw = W1h - inv*W1c ; Wst[1] = W2 ; Wst[2] = W1h0
__global__ __launch_bounds__(256) void prep_k(const float* __restrict__ W1,
                                              const float* __restrict__ W2,
                                              float* __restrict__ Wc,
                                              unsigned short* __restrict__ Wst) {
    int i = blockIdx.x * 256 + threadIdx.x;
    const float inv = 1.0f / 63.0f;
    if (i < 3 * HID * KS) {
        int mat = i / (HID * KS);
        int rem = i % (HID * KS);
        int n = rem / KS;          // output col 0..255
        int k = rem % KS;          // stacked k 0..767
        int region = k >> 8;       // 0: hi, 1: lo, 2: hi
        int ksrc = k & 255;
        float val;
        if (mat == 0)      val = W1[ksrc * HID + n] - inv * W1[(HID + ksrc) * HID + n];
        else if (mat == 1) val = W2[ksrc * HID + n];
        else               val = W1[(2 * HID + ksrc) * HID + n];
        unsigned short hi = f2bf(val);
        Wst[i] = (region == 1) ? f2bf(val - bf2f(hi)) : hi;
    } else {
        int j = i - 3 * HID * KS;
        if (j < HID * HID) {
            int k = j >> 8, n = j & 255;
            Wc[j] = inv * W1[(HID + k) * HID + n];
        }
    }
}

// ---- embedding gather -> split bf16 pair (h stored ONLY as hi/lo) ----
__global__ __launch_bounds__(256) void embed_k(const int* __restrict__ ids,
                                               const float* __restrict__ emb,
                                               unsigned short* __restrict__ hh,
                                               unsigned short* __restrict__ hl) {
    int idx = blockIdx.x * 256 + threadIdx.x;   // one 4-elem chunk
    if (idx >= NROWS * HID / 4) return;
    int r = idx >> 6, c4 = idx & 63;
    float4 v = ((const float4*)(emb + (size_t)ids[r] * HID))[c4];
    ushort4 hi, lo;
    hi.x = f2bf(v.x); lo.x = f2bf(v.x - bf2f(hi.x));
    hi.y = f2bf(v.y); lo.y = f2bf(v.y - bf2f(hi.y));
    hi.z = f2bf(v.z); lo.z = f2bf(v.z - bf2f(hi.z));
    hi.w = f2bf(v.w); lo.w = f2bf(v.w - bf2f(hi.w));
    size_t o = (size_t)r * HID + c4 * 4;
    *(ushort4*)(hh + o) = hi;
    *(ushort4*)(hl + o) = lo;
}

// ---- rowsum + tiny per-batch GEMM: T[b] = (sum_m h[b,m,:]) @ Wc ----
__global__ __launch_bounds__(256) void rowsumT_k(const unsigned short* __restrict__ hh,
                                                 const unsigned short* __restrict__ hl,
                                                 const float* __restrict__ Wc,
                                                 float* __restrict__ T) {
    int b = blockIdx.x, t = threadIdx.x;
    __shared__ float S[HID];
    const unsigned short* ph = hh + (size_t)b * NM * HID;
    const unsigned short* pl = hl + (size_t)b * NM * HID;
    float s = 0.f;
    #pragma unroll 8
    for (int m = 0; m < NM; ++m) s += bf2f(ph[m * HID + t]) + bf2f(pl[m * HID + t]);
    S[t] = s;
    __syncthreads();
    float acc = 0.f;
    #pragma unroll 8
    for (int k = 0; k < HID; ++k) acc += S[k] * Wc[k * HID + t];
    T[b * HID + t] = acc;
}

// ---- main split-bf16 MFMA GEMM: C = [Ah,Ah,Al](M x 768) @ Bt^T + epilogue ----
// EPI 0: u0 = AB + b1                       (f32 out)
// EPI 1: act = relu(AB + T[batch] + u0)     (split bf16 out)
// EPI 2: h  += AB + b2                      (h pair in/out, split bf16)
template<int EPI>
__global__ __launch_bounds__(256) void gemm_mfma(
    const unsigned short* __restrict__ Ahi, const unsigned short* __restrict__ Alo,
    const unsigned short* __restrict__ Bt,   // [256 n][768 k] bf16 stacked
    float* __restrict__ Cf,
    unsigned short* __restrict__ Chi, unsigned short* __restrict__ Clo,
    const float* __restrict__ bias,
    const float* __restrict__ Trow, const float* __restrict__ U0,
    unsigned short* __restrict__ Hhi, unsigned short* __restrict__ Hlo)
{
    __shared__ __align__(16) unsigned short As[BM * BK];  // [128][32] 8KB
    __shared__ __align__(16) unsigned short Bs[BN * BK];  // [128][32] 8KB

    const int tid  = threadIdx.x;
    const int row0 = blockIdx.x * BM;
    const int n0   = blockIdx.y * BN;
    const int w  = tid >> 6;
    const int wm = w >> 1, wn = w & 1;
    const int lane = tid & 63;
    const int l15 = lane & 15;
    const int lk8 = (lane >> 4) * 8;

    const int srow = tid >> 2;          // staging row within 64-row group
    const int scol = (tid & 3) * 8;     // staging col (shorts)

    f32x4 acc[4][4];
    #pragma unroll
    for (int m = 0; m < 4; ++m)
        #pragma unroll
        for (int n = 0; n < 4; ++n) acc[m][n] = (f32x4){0.f, 0.f, 0.f, 0.f};

    for (int ks = 0; ks < KS / BK; ++ks) {
        const int k0 = ks * BK;
        const unsigned short* Asrc = (k0 < 512) ? (Ahi + (k0 & 255)) : (Alo + (k0 - 512));
        const unsigned short* Bsrc = Bt + k0;
        __syncthreads();
        gload_lds16(Asrc + (size_t)(row0 + srow) * HID + scol,      &As[(size_t)tid * 8]);
        gload_lds16(Asrc + (size_t)(row0 + 64 + srow) * HID + scol, &As[2048 + (size_t)tid * 8]);
        gload_lds16(Bsrc + (size_t)(n0 + srow) * KS + scol,         &Bs[(size_t)tid * 8]);
        gload_lds16(Bsrc + (size_t)(n0 + 64 + srow) * KS + scol,    &Bs[2048 + (size_t)tid * 8]);
        __syncthreads();

        bf16x8 af[4], bfr[4];
        #pragma unroll
        for (int m = 0; m < 4; ++m)
            af[m] = *(const bf16x8*)&As[(wm * 64 + m * 16 + l15) * BK + lk8];
        #pragma unroll
        for (int n = 0; n < 4; ++n)
            bfr[n] = *(const bf16x8*)&Bs[(wn * 64 + n * 16 + l15) * BK + lk8];
        #pragma unroll
        for (int m = 0; m < 4; ++m)
            #pragma unroll
            for (int n = 0; n < 4; ++n)
                acc[m][n] = __builtin_amdgcn_mfma_f32_16x16x32_bf16(af[m], bfr[n], acc[m][n], 0, 0, 0);
    }

    // epilogue: C/D layout col = lane&15, row = (lane>>4)*4 + r
    #pragma unroll
    for (int m = 0; m < 4; ++m) {
        #pragma unroll
        for (int n = 0; n < 4; ++n) {
            #pragma unroll
            for (int r = 0; r < 4; ++r) {
                int row = row0 + wm * 64 + m * 16 + (lane >> 4) * 4 + r;
                int col = n0 + wn * 64 + n * 16 + l15;
                size_t o = (size_t)row * HID + col;
                float v = acc[m][n][r];
                if (EPI == 0) {
                    Cf[o] = v + bias[col];
                } else if (EPI == 1) {
                    float a = v + Trow[(row >> 6) * HID + col] + U0[o];
                    a = fmaxf(a, 0.f);
                    unsigned short hi = f2bf(a);
                    Chi[o] = hi;
                    Clo[o] = f2bf(a - bf2f(hi));
                } else {
                    float hv = bf2f(Hhi[o]) + bf2f(Hlo[o]) + v + bias[col];
                    unsigned short hi = f2bf(hv);
                    Hhi[o] = hi;
                    Hlo[o] = f2bf(hv - bf2f(hi));
                }
            }
        }
    }
}

// ---- decoder: logits = h @ Wd + bd ----
__global__ __launch_bounds__(256) void decoder_k(const unsigned short* __restrict__ hh,
                                                 const unsigned short* __restrict__ hl,
                                                 const float* __restrict__ Wd,
                                                 const float* __restrict__ bd,
                                                 float* __restrict__ out) {
    __shared__ float hs[16][260];
    __shared__ float Wds[HID * NACT];
    const int tid = threadIdx.x;
    const int r0 = blockIdx.x * 16;
    #pragma unroll
    for (int j = 0; j < 4; ++j) {
        int idx = tid + j * 256;        // 1024 chunks of 4 elems
        int r = idx >> 6, c4 = idx & 63;
        size_t o = (size_t)(r0 + r) * HID + c4 * 4;
        ushort4 a = *(const ushort4*)(hh + o);
        ushort4 b = *(const ushort4*)(hl + o);
        hs[r][c4 * 4 + 0] = bf2f(a.x) + bf2f(b.x);
        hs[r][c4 * 4 + 1] = bf2f(a.y) + bf2f(b.y);
        hs[r][c4 * 4 + 2] = bf2f(a.z) + bf2f(b.z);
        hs[r][c4 * 4 + 3] = bf2f(a.w) + bf2f(b.w);
    }
    #pragma unroll
    for (int j = 0; j < 16; ++j) Wds[tid + j * 256] = Wd[tid + j * 256];
    __syncthreads();

    const int row = tid >> 4;
    const int a   = tid & 15;
    float acc = bd[a];
    #pragma unroll 8
    for (int k = 0; k < HID; ++k) acc += hs[row][k] * Wds[k * NACT + a];
    out[(size_t)(r0 + row) * NACT + a] = acc;
}

extern "C" void kernel_launch(void* const* d_in, const int* in_sizes, int n_in,
                              void* d_out, int out_size, void* d_ws, size_t ws_size,
                              hipStream_t stream) {
    const int*   ids = (const int*)d_in[0];
    const float* emb = (const float*)d_in[1];
    const float* W1  = (const float*)d_in[2];
    const float* b1  = (const float*)d_in[3];
    const float* W2  = (const float*)d_in[4];
    const float* b2  = (const float*)d_in[5];
    const float* Wd  = (const float*)d_in[6];
    const float* bd  = (const float*)d_in[7];
    float* out = (float*)d_out;

    char* p = (char*)d_ws;
    float* u0 = (float*)p;           p += (size_t)NROWS * HID * 4;   // 64 MB
    float* T  = (float*)p;           p += (size_t)NB * HID * 4;      // 1 MB
    float* Wc = (float*)p;           p += (size_t)HID * HID * 4;     // 256 KB
    unsigned short* hh   = (unsigned short*)p; p += (size_t)NROWS * HID * 2;  // 32 MB
    unsigned short* hl   = (unsigned short*)p; p += (size_t)NROWS * HID * 2;
    unsigned short* acth = (unsigned short*)p; p += (size_t)NROWS * HID * 2;
    unsigned short* actl = (unsigned short*)p; p += (size_t)NROWS * HID * 2;
    unsigned short* Wst  = (unsigned short*)p;                        // 3*256*768*2 = 1.125 MB

    const unsigned short* WstAw = Wst;
    const unsigned short* WstW2 = Wst + (size_t)HID * KS;
    const unsigned short* WstH0 = Wst + (size_t)2 * HID * KS;

    prep_k<<<(3 * HID * KS + HID * HID + 255) / 256, 256, 0, stream>>>(W1, W2, Wc, Wst);
    embed_k<<<(NROWS * HID / 4 + 255) / 256, 256, 0, stream>>>(ids, emb, hh, hl);

    dim3 g(NROWS / BM, HID / BN);   // (512, 2)
    // u0 = h0 @ W1h0 + b1
    gemm_mfma<0><<<g, 256, 0, stream>>>(hh, hl, WstH0, u0, nullptr, nullptr,
                                        b1, nullptr, nullptr, nullptr, nullptr);

    for (int s = 0; s < NSTEPS; ++s) {
        rowsumT_k<<<NB, 256, 0, stream>>>(hh, hl, Wc, T);
        gemm_mfma<1><<<g, 256, 0, stream>>>(hh, hl, WstAw, nullptr, acth, actl,
                                            nullptr, T, u0, nullptr, nullptr);
        gemm_mfma<2><<<g, 256, 0, stream>>>(acth, actl, WstW2, nullptr, nullptr, nullptr,
                                            b2, nullptr, nullptr, hh, hl);
    }

    decoder_k<<<NROWS / 16, 256, 0, stream>>>(hh, hl, Wd, bd, out);
}

// Round 3
// 553.619 us; speedup vs baseline: 2.2445x; 1.3564x over previous
//
#include <hip/hip_runtime.h>

#define HID 256
#define NB 1024
#define NM 64
#define NROWS (NB*NM)   // 65536
#define NACT 16
#define KSA 1536        // stacked K for step-0 phase A: [h0@W1h0 stack | h@Aw stack]
#define KSW 768

typedef __bf16 bf16x8 __attribute__((ext_vector_type(8)));
typedef float  f32x4  __attribute__((ext_vector_type(4)));

__device__ __forceinline__ void gload_lds16(const void* g, void* l) {
    __builtin_amdgcn_global_load_lds(
        (const __attribute__((address_space(1))) void*)g,
        (__attribute__((address_space(3))) void*)l, 16, 0, 0);
}
__device__ __forceinline__ unsigned short f2bf(float x) {
    union { float f; unsigned u; } v; v.f = x;
    unsigned r = v.u + 0x7fff + ((v.u >> 16) & 1);
    return (unsigned short)(r >> 16);
}
__device__ __forceinline__ float bf2f(unsigned short b) {
    union { float f; unsigned u; } v; v.u = ((unsigned)b) << 16;
    return v.f;
}
__device__ __forceinline__ float unpackH(unsigned int p) {
    return bf2f((unsigned short)p) + bf2f((unsigned short)(p >> 16));
}
__device__ __forceinline__ unsigned int packH(float x) {
    unsigned short hi = f2bf(x);
    unsigned short lo = f2bf(x - bf2f(hi));
    return (unsigned)hi | ((unsigned)lo << 16);
}

// ---- prep: WA [256n][1536k] = [W1h0 hi|lo|hi , Aw hi|lo|hi]; WB [256][768] = W2 stack; Wc f32 ----
__global__ __launch_bounds__(256) void prep_k(const float* __restrict__ W1,
                                              const float* __restrict__ W2,
                                              unsigned short* __restrict__ WA,
                                              unsigned short* __restrict__ WB,
                                              float* __restrict__ Wc) {
    int i = blockIdx.x * 256 + threadIdx.x;
    const float inv = 1.0f / 63.0f;
    if (i < 256 * KSA) {
        int n = i / KSA, k = i % KSA;
        float val; int r;
        if (k < 768) { r = k >> 8; int ks = k & 255; val = W1[(512 + ks) * HID + n]; }
        else { int kk = k - 768; r = kk >> 8; int ks = kk & 255;
               val = W1[ks * HID + n] - inv * W1[(256 + ks) * HID + n]; }
        unsigned short hi = f2bf(val);
        WA[i] = (r == 1) ? f2bf(val - bf2f(hi)) : hi;
    } else if (i < 256 * KSA + 256 * KSW) {
        int j = i - 256 * KSA;
        int n = j / KSW, k = j % KSW;
        int r = k >> 8, ks = k & 255;
        float val = W2[ks * HID + n];
        unsigned short hi = f2bf(val);
        WB[j] = (r == 1) ? f2bf(val - bf2f(hi)) : hi;
    } else {
        int j = i - 256 * KSA - 256 * KSW;
        if (j < HID * HID) {
            int k = j >> 8, n = j & 255;
            Wc[j] = inv * W1[(256 + k) * HID + n];
        }
    }
}

// ---- embedding gather -> packed split-bf16 H (u32 = hi | lo<<16) ----
__global__ __launch_bounds__(256) void embed_k(const int* __restrict__ ids,
                                               const float* __restrict__ emb,
                                               unsigned int* __restrict__ H) {
    int idx = blockIdx.x * 256 + threadIdx.x;
    if (idx >= NROWS * HID / 4) return;
    int r = idx >> 6, c4 = idx & 63;
    float4 v = ((const float4*)(emb + (size_t)ids[r] * HID))[c4];
    uint4 o;
    o.x = packH(v.x); o.y = packH(v.y); o.z = packH(v.z); o.w = packH(v.w);
    ((uint4*)(H + (size_t)r * HID))[c4] = o;
}

// ---- rowsum + tiny per-batch GEMM: T[b] = (sum_m h[b,m,:]) @ Wc ----
__global__ __launch_bounds__(256) void rowsumT_k(const unsigned int* __restrict__ H,
                                                 const float* __restrict__ Wc,
                                                 float* __restrict__ T) {
    int b = blockIdx.x, t = threadIdx.x;
    __shared__ float S[HID];
    const unsigned int* hb = H + (size_t)b * NM * HID;
    float s = 0.f;
    #pragma unroll 8
    for (int m = 0; m < NM; ++m) s += unpackH(hb[m * HID + t]);
    S[t] = s;
    __syncthreads();
    float acc = 0.f;
    #pragma unroll 8
    for (int k = 0; k < HID; ++k) acc += S[k] * Wc[k * HID + t];
    T[b * HID + t] = acc;
}

// ---- fused comm step: one block per batch (64 rows x 256 cols) ----
// phase A: acc = h@Aw-stack (+ h0@W1h0-stack if FIRST, writing u0 mid-loop)
//          preact = acc + T[b] + u0(; b1 if FIRST); act = relu -> split bf16 -> LDS
// phase B: acc = act@W2-stack; hnew = h + acc + b2 -> packed H
template<bool FIRST>
__global__ __launch_bounds__(512, 4) void fused_step(
    unsigned int* __restrict__ H, float* __restrict__ U0,
    const float* __restrict__ T, const unsigned short* __restrict__ WA,
    const unsigned short* __restrict__ WB, const float* __restrict__ b1,
    const float* __restrict__ b2)
{
    __shared__ unsigned short hLDS[32768];  // hi: bytes [0,32K), lo: [32K,64K)
    __shared__ unsigned short Bls[8192];    // 16 KB weight step-tile

    const int tid = threadIdx.x;
    const int lane = tid & 63;
    const int w = tid >> 6;
    const int wm = w >> 2, wn = w & 3;
    const int l15 = lane & 15, g = lane >> 4;
    const int b = blockIdx.x;
    const size_t rowbase = (size_t)b * 64;
    char* ldsC = (char*)hLDS;

    // ---- stage h: 64x256 packed u32 -> split hi/lo, XOR-swizzled ----
    {
        int r = tid >> 3;
        int c0 = (tid & 7) * 32;
        const unsigned int* src = H + (rowbase + r) * HID + c0;
        int rx = (r & 7) << 4;
        #pragma unroll
        for (int j = 0; j < 8; ++j) {
            uint4 v = *(const uint4*)(src + j * 4);
            unsigned int h01 = (v.x & 0xffffu) | (v.y << 16);
            unsigned int h23 = (v.z & 0xffffu) | (v.w << 16);
            unsigned int l01 = (v.x >> 16) | (v.y & 0xffff0000u);
            unsigned int l23 = (v.z >> 16) | (v.w & 0xffff0000u);
            int byte = (r * 512 + (c0 + j * 4) * 2) ^ rx;
            *(uint2*)(ldsC + byte) = make_uint2(h01, h23);
            *(uint2*)(ldsC + 32768 + byte) = make_uint2(l01, l23);
        }
    }

    // lane-invariant fragment address parts
    const int rxA = (l15 & 7) << 4;
    int lbA[2], Bbyte[4];
    #pragma unroll
    for (int mt = 0; mt < 2; ++mt)
        lbA[mt] = (wm * 32 + mt * 16 + l15) * 512 + g * 16;
    #pragma unroll
    for (int nt = 0; nt < 4; ++nt) {
        int n = wn * 64 + nt * 16 + l15;
        Bbyte[nt] = n * 64 + ((g ^ ((n >> 1) & 3)) << 4);
    }

    f32x4 acc[2][4];
    #pragma unroll
    for (int mt = 0; mt < 2; ++mt)
        #pragma unroll
        for (int nt = 0; nt < 4; ++nt) acc[mt][nt] = (f32x4){0.f, 0.f, 0.f, 0.f};

    // ---- phase A K-loop ----
    {
        const int nk = FIRST ? 48 : 24;
        const int kstart = FIRST ? 0 : 768;
        for (int t = 0; t < nk; ++t) {
            const int k0 = kstart + t * 32;
            if (t > 0) __syncthreads();
            // stage B step-tile (source pre-swizzled)
            #pragma unroll
            for (int j = 0; j < 2; ++j) {
                int c = w * 128 + j * 64 + lane;
                int n = c >> 2, s = c & 3;
                int ss = s ^ ((n >> 1) & 3);
                gload_lds16(WA + (size_t)n * KSA + k0 + ss * 8,
                            (char*)Bls + c * 16);
            }
            __syncthreads();
            const int reg = (k0 >> 8) % 3;
            const int aoff = (reg == 2) ? 32768 : 0;
            const int kk2 = (k0 & 255) * 2;
            bf16x8 a0 = *(const bf16x8*)(ldsC + (((lbA[0] + kk2) ^ rxA) + aoff));
            bf16x8 a1 = *(const bf16x8*)(ldsC + (((lbA[1] + kk2) ^ rxA) + aoff));
            #pragma unroll
            for (int nt = 0; nt < 4; ++nt) {
                bf16x8 bv = *(const bf16x8*)((char*)Bls + Bbyte[nt]);
                acc[0][nt] = __builtin_amdgcn_mfma_f32_16x16x32_bf16(a0, bv, acc[0][nt], 0, 0, 0);
                acc[1][nt] = __builtin_amdgcn_mfma_f32_16x16x32_bf16(a1, bv, acc[1][nt], 0, 0, 0);
            }
            if (FIRST && t == 23) {
                // acc == h0@W1h0 here -> write u0 = acc + b1
                #pragma unroll
                for (int nt = 0; nt < 4; ++nt) {
                    int col = wn * 64 + nt * 16 + l15;
                    float bb = b1[col];
                    #pragma unroll
                    for (int mt = 0; mt < 2; ++mt)
                        #pragma unroll
                        for (int q = 0; q < 4; ++q) {
                            int row = wm * 32 + mt * 16 + g * 4 + q;
                            U0[(rowbase + row) * HID + col] = acc[mt][nt][q] + bb;
                        }
                }
            }
        }
    }

    // ---- epilogue A: preact -> relu -> split -> act into (reused) h LDS ----
    {
        float tv[4], ex[4];
        #pragma unroll
        for (int nt = 0; nt < 4; ++nt) {
            int col = wn * 64 + nt * 16 + l15;
            tv[nt] = T[b * HID + col];
            ex[nt] = FIRST ? b1[col] : 0.f;
        }
        float u0v[2][4][4];
        if (!FIRST) {
            #pragma unroll
            for (int mt = 0; mt < 2; ++mt)
                #pragma unroll
                for (int nt = 0; nt < 4; ++nt)
                    #pragma unroll
                    for (int q = 0; q < 4; ++q) {
                        int row = wm * 32 + mt * 16 + g * 4 + q;
                        int col = wn * 64 + nt * 16 + l15;
                        u0v[mt][nt][q] = U0[(rowbase + row) * HID + col];
                    }
        }
        __syncthreads();   // all phase-A LDS reads complete before overwrite
        #pragma unroll
        for (int mt = 0; mt < 2; ++mt)
            #pragma unroll
            for (int nt = 0; nt < 4; ++nt)
                #pragma unroll
                for (int q = 0; q < 4; ++q) {
                    int row = wm * 32 + mt * 16 + g * 4 + q;
                    int col = wn * 64 + nt * 16 + l15;
                    float pre = acc[mt][nt][q] + tv[nt] + (FIRST ? ex[nt] : u0v[mt][nt][q]);
                    float a = fmaxf(pre, 0.f);
                    unsigned short hi = f2bf(a);
                    unsigned short lo = f2bf(a - bf2f(hi));
                    int byte = (row * 512 + col * 2) ^ ((row & 7) << 4);
                    *(unsigned short*)(ldsC + byte) = hi;
                    *(unsigned short*)(ldsC + 32768 + byte) = lo;
                    acc[mt][nt][q] = 0.f;   // reset for phase B
                }
        __syncthreads();   // act visible to all
    }

    // ---- phase B K-loop (act @ W2-stack) ----
    for (int t = 0; t < 24; ++t) {
        const int k0 = t * 32;
        if (t > 0) __syncthreads();
        #pragma unroll
        for (int j = 0; j < 2; ++j) {
            int c = w * 128 + j * 64 + lane;
            int n = c >> 2, s = c & 3;
            int ss = s ^ ((n >> 1) & 3);
            gload_lds16(WB + (size_t)n * KSW + k0 + ss * 8,
                        (char*)Bls + c * 16);
        }
        __syncthreads();
        const int reg = k0 >> 8;
        const int aoff = (reg == 2) ? 32768 : 0;
        const int kk2 = (k0 & 255) * 2;
        bf16x8 a0 = *(const bf16x8*)(ldsC + (((lbA[0] + kk2) ^ rxA) + aoff));
        bf16x8 a1 = *(const bf16x8*)(ldsC + (((lbA[1] + kk2) ^ rxA) + aoff));
        #pragma unroll
        for (int nt = 0; nt < 4; ++nt) {
            bf16x8 bv = *(const bf16x8*)((char*)Bls + Bbyte[nt]);
            acc[0][nt] = __builtin_amdgcn_mfma_f32_16x16x32_bf16(a0, bv, acc[0][nt], 0, 0, 0);
            acc[1][nt] = __builtin_amdgcn_mfma_f32_16x16x32_bf16(a1, bv, acc[1][nt], 0, 0, 0);
        }
    }

    // ---- epilogue B: hnew = h + delta + b2 -> packed H ----
    {
        float b2v[4];
        #pragma unroll
        for (int nt = 0; nt < 4; ++nt) b2v[nt] = b2[wn * 64 + nt * 16 + l15];
        #pragma unroll
        for (int mt = 0; mt < 2; ++mt)
            #pragma unroll
            for (int nt = 0; nt < 4; ++nt)
                #pragma unroll
                for (int q = 0; q < 4; ++q) {
                    int row = wm * 32 + mt * 16 + g * 4 + q;
                    int col = wn * 64 + nt * 16 + l15;
                    size_t o = (rowbase + row) * HID + col;
                    float hnew = unpackH(H[o]) + acc[mt][nt][q] + b2v[nt];
                    H[o] = packH(hnew);
                }
    }
}

// ---- decoder: logits = h @ Wd + bd ----
__global__ __launch_bounds__(256) void decoder_k(const unsigned int* __restrict__ H,
                                                 const float* __restrict__ Wd,
                                                 const float* __restrict__ bd,
                                                 float* __restrict__ out) {
    __shared__ float hs[16][260];
    __shared__ float Wds[HID * NACT];
    const int tid = threadIdx.x;
    const int r0 = blockIdx.x * 16;
    #pragma unroll
    for (int j = 0; j < 4; ++j) {
        int idx = tid + j * 256;
        int r = idx >> 6, c4 = idx & 63;
        uint4 v = *(const uint4*)(H + (size_t)(r0 + r) * HID + c4 * 4);
        hs[r][c4 * 4 + 0] = unpackH(v.x);
        hs[r][c4 * 4 + 1] = unpackH(v.y);
        hs[r][c4 * 4 + 2] = unpackH(v.z);
        hs[r][c4 * 4 + 3] = unpackH(v.w);
    }
    #pragma unroll
    for (int j = 0; j < 16; ++j) Wds[tid + j * 256] = Wd[tid + j * 256];
    __syncthreads();
    const int row = tid >> 4;
    const int a = tid & 15;
    float acc = bd[a];
    #pragma unroll 8
    for (int k = 0; k < HID; ++k) acc += hs[row][k] * Wds[k * NACT + a];
    out[(size_t)(r0 + row) * NACT + a] = acc;
}

extern "C" void kernel_launch(void* const* d_in, const int* in_sizes, int n_in,
                              void* d_out, int out_size, void* d_ws, size_t ws_size,
                              hipStream_t stream) {
    const int*   ids = (const int*)d_in[0];
    const float* emb = (const float*)d_in[1];
    const float* W1  = (const float*)d_in[2];
    const float* b1  = (const float*)d_in[3];
    const float* W2  = (const float*)d_in[4];
    const float* b2  = (const float*)d_in[5];
    const float* Wd  = (const float*)d_in[6];
    const float* bd  = (const float*)d_in[7];
    float* out = (float*)d_out;

    char* p = (char*)d_ws;
    unsigned int* H = (unsigned int*)p;  p += (size_t)NROWS * HID * 4;   // 64 MB
    float* U0 = (float*)p;               p += (size_t)NROWS * HID * 4;   // 64 MB
    float* T  = (float*)p;               p += (size_t)NB * HID * 4;      // 1 MB
    float* Wc = (float*)p;               p += (size_t)HID * HID * 4;
    unsigned short* WA = (unsigned short*)p; p += (size_t)256 * KSA * 2; // 768 KB
    unsigned short* WB = (unsigned short*)p;                             // 384 KB

    prep_k<<<(256 * KSA + 256 * KSW + HID * HID + 255) / 256, 256, 0, stream>>>(W1, W2, WA, WB, Wc);
    embed_k<<<(NROWS * HID / 4 + 255) / 256, 256, 0, stream>>>(ids, emb, H);

    rowsumT_k<<<NB, 256, 0, stream>>>(H, Wc, T);
    fused_step<true><<<NB, 512, 0, stream>>>(H, U0, T, WA, WB, b1, b2);
    for (int s = 1; s < 4; ++s) {
        rowsumT_k<<<NB, 256, 0, stream>>>(H, Wc, T);
        fused_step<false><<<NB, 512, 0, stream>>>(H, U0, T, WA, WB, b1, b2);
    }
    decoder_k<<<NROWS / 16, 256, 0, stream>>>(H, Wd, bd, out);
}